// Round 4
// baseline (400.801 us; speedup 1.0000x reference)
//
#include <hip/hip_runtime.h>

// GCN: 3x GCNConv(sym-norm, self-loops) + ReLU, mean-pool per graph, FC.
// Strategy: fold dinv into per-layer G = dinv .* (X@W); build dst-CSR once
// per call so aggregation is atomic-free.
// R1-R7: store-coalescing chase falsified. R8: zero global atomics in CSR
//   build. R9/R11/R12: L2-residency bets failed. R10: G fp16 (1 line/edge).
//   R13: 1024-wide bucket/place -> 405us. R14: fuse next-layer GEMM into
//   agg epilogue -> 376us (agg 59us, FETCH 121MB, VALUBusy 28%).
// R15/16: XCD feature-split FALSIFIED (FETCH halved but dur worse: agg is
//   latency-exposure bound; never shrink the 64B request).
// R17: pipelined gather (chunk16, col prefetch 1 ahead, int4 cols, masked
//   tail) -> 358.7us; agg 48us, VALUBusy 44%, FETCH 103MB. Model: per-CU
//   MSHR cap x avg latency (~50% L2 hit, G 6.4MB > 4MB XCD L2).
// R18: 2-pass src-partitioned agg. Each CSR row split [src<50K | src>=50K]
//   (mid[] cursor from k_place). Per layer: p1 gathers lower half only
//   (WS 3.2MB -> L2-resident on every XCD), raw sums -> Pbuf fp32 NT;
//   p2 gathers upper half + Pbuf + dinv/bias/relu + fused GEMM. Kernel
//   boundary = temporal separation; latency ~400 -> ~200cy. Predict agg
//   pass 12-17us each, FETCH ~33/46MB, total ~315us.

#include <hip/hip_fp16.h>

#define NN 100000
#define HALFN 50000
#define EE 3200000
#define FIN 128
#define HID 32
#define NGR 256
#define NC 10
#define NBUK 256
#define BRANGE 391    // 256*391 = 100096 >= NN
#define BSLACK 13400  // mean 12500, sd ~112 -> ~8 sigma slack (input is fixed)
#define TILE 8192

typedef _Float16 h2 __attribute__((ext_vector_type(2)));
typedef _Float16 h4 __attribute__((ext_vector_type(4)));
typedef float f2 __attribute__((ext_vector_type(2)));
typedef int i4u __attribute__((ext_vector_type(4), aligned(4)));

#define NTL(p) __builtin_nontemporal_load(p)
#define NTL4(p) __builtin_nontemporal_load(reinterpret_cast<const i4u*>(p))

__global__ void k_init(int* __restrict__ bcur) {
  int t = threadIdx.x;
  if (t < NBUK) bcur[t] = t * BSLACK;
}

// Pass A: LDS multisplit of one 8192-edge tile into 256 dst-buckets.
__global__ __launch_bounds__(1024) void k_bucket(const int* __restrict__ ei,
                                                 int* __restrict__ bcur,
                                                 long long* __restrict__ bpair) {
  __shared__ int hist[NBUK];
  __shared__ int bexc[NBUK];
  __shared__ int cnt[NBUK];
  __shared__ int gofs[NBUK];
  __shared__ long long sorted[TILE];  // 64 KB
  int t = threadIdx.x;
  const int* src = ei;
  const int* dst = ei + EE;
  int e0 = blockIdx.x * TILE;
  int tn = EE - e0;
  if (tn > TILE) tn = TILE;

  if (t < NBUK) { hist[t] = 0; cnt[t] = 0; }
  __syncthreads();

  for (int i = t; i < tn; i += 1024) {
    int d = __builtin_nontemporal_load(&dst[e0 + i]);
    atomicAdd(&hist[d / BRANGE], 1);
  }
  __syncthreads();

  int hv = 0;
  if (t < NBUK) { hv = hist[t]; bexc[t] = hv; }
  __syncthreads();
#pragma unroll
  for (int off = 1; off < NBUK; off <<= 1) {
    int x = 0;
    if (t < NBUK && t >= off) x = bexc[t - off];
    __syncthreads();
    if (t < NBUK) bexc[t] += x;
    __syncthreads();
  }
  if (t < NBUK) {
    int inc = bexc[t];
    bexc[t] = inc - hv;
    if (hv > 0) gofs[t] = atomicAdd(&bcur[t], hv);  // ~65K atomics total
  }
  __syncthreads();

  for (int i = t; i < tn; i += 1024) {
    int d = dst[e0 + i];
    int s = src[e0 + i];
    int q = d / BRANGE;
    int p = bexc[q] + atomicAdd(&cnt[q], 1);
    sorted[p] = ((long long)(unsigned)d << 32) | (unsigned)s;
  }
  __syncthreads();

  for (int i = t; i < tn; i += 1024) {
    long long pr = sorted[i];
    int q = (int)(unsigned)(pr >> 32) / BRANGE;
    __builtin_nontemporal_store(pr, &bpair[(size_t)gofs[q] + (i - bexc[q])]);
  }
}

// Fused CSR finalize: one 1024-thread block per bucket, zero global atomics.
// R18: rows are segmented [src<HALFN | src>=HALFN]; mid[n] = split point.
__global__ __launch_bounds__(1024) void k_place(const long long* __restrict__ bpair,
                                                const int* __restrict__ bcur,
                                                float* __restrict__ dinv,
                                                int* __restrict__ row_ptr,
                                                int* __restrict__ mid,
                                                int* __restrict__ col) {
  __shared__ int bs[NBUK];
  __shared__ int cnt[BRANGE];   // total per dst; becomes cursor A
  __shared__ int cntA[BRANGE];  // src<HALFN per dst; becomes cursor B
  __shared__ int sc[1024];
  int b = blockIdx.x, t = threadIdx.x;

  if (t < NBUK) bs[t] = bcur[t] - t * BSLACK;
  __syncthreads();
#pragma unroll
  for (int off = 1; off < NBUK; off <<= 1) {
    int x = 0;
    if (t < NBUK && t >= off) x = bs[t - off];
    __syncthreads();
    if (t < NBUK) bs[t] += x;
    __syncthreads();
  }
  __syncthreads();
  int sz = bcur[b] - b * BSLACK;
  int colbase = bs[b] - sz;

  if (t < BRANGE) { cnt[t] = 0; cntA[t] = 0; }
  __syncthreads();

  int lo = b * BRANGE;
  int nnode = NN - lo;
  if (nnode > BRANGE) nnode = BRANGE;
  size_t e0 = (size_t)b * BSLACK;

  for (int i = t; i < sz; i += 1024) {
    long long pr = bpair[e0 + i];
    int d = (int)(unsigned)(pr >> 32);
    int s = (int)(unsigned)(pr & 0xffffffffLL);
    atomicAdd(&cnt[d - lo], 1);
    if (s < HALFN) atomicAdd(&cntA[d - lo], 1);
  }
  __syncthreads();

  int v = (t < BRANGE) ? cnt[t] : 0;
  sc[t] = v;
  __syncthreads();
#pragma unroll
  for (int off = 1; off < 1024; off <<= 1) {
    int x = (t >= off) ? sc[t - off] : 0;
    __syncthreads();
    sc[t] += x;
    __syncthreads();
  }
  int excl = sc[t] - v;
  if (t < nnode) {
    row_ptr[lo + t] = colbase + excl;
    dinv[lo + t] = rsqrtf((float)(v + 1));  // +1 = self-loop
  }
  if (t < BRANGE) {
    int ca = cntA[t];
    cnt[t] = colbase + excl;            // cursor A (lower-half segment)
    cntA[t] = colbase + excl + ca;      // cursor B (upper-half segment)
    if (t < nnode) mid[lo + t] = colbase + excl + ca;
  }
  if (b == NBUK - 1 && t == 0) row_ptr[NN] = EE;
  __syncthreads();

  for (int i = t; i < sz; i += 1024) {
    long long pr = bpair[e0 + i];
    int d = (int)(unsigned)(pr >> 32);
    int s = (int)(unsigned)(pr & 0xffffffffLL);
    int* cptr = (s < HALFN) ? &cnt[d - lo] : &cntA[d - lo];
    int pos = atomicAdd(cptr, 1);
    col[pos] = s;
  }
}

// G = dinv .* (X @ W), stored fp16 [node][32] (64B rows = 1 cache line).
template <int K>
__global__ __launch_bounds__(256) void k_gemm(const float* __restrict__ X,
                                              const float* __restrict__ W,
                                              const float* __restrict__ dinv,
                                              _Float16* __restrict__ Gout) {
  __shared__ float Wl[K * HID];
  __shared__ float xs[128 * 36];
  int t = threadIdx.x;
  for (int i = t; i < K * HID; i += 256) Wl[i] = W[i];
  int node0 = blockIdx.x * 128;
  int ng = t >> 3, f4 = t & 7;
  float acc[4][4];
#pragma unroll
  for (int j = 0; j < 4; j++)
#pragma unroll
    for (int c = 0; c < 4; c++) acc[j][c] = 0.f;

  for (int kc = 0; kc < K; kc += 32) {
    __syncthreads();
#pragma unroll
    for (int j = 0; j < 4; j++) {
      int idx = t + 256 * j;
      int r = idx >> 3, c4 = idx & 7;
      int row = node0 + r;
      if (row >= NN) row = NN - 1;
      float4 v = *reinterpret_cast<const float4*>(&X[(size_t)row * K + kc + c4 * 4]);
      *reinterpret_cast<float4*>(&xs[r * 36 + c4 * 4]) = v;
    }
    __syncthreads();
#pragma unroll
    for (int k4 = 0; k4 < 8; k4++) {
      float4 xv[4];
#pragma unroll
      for (int j = 0; j < 4; j++)
        xv[j] = *reinterpret_cast<const float4*>(&xs[(ng * 4 + j) * 36 + k4 * 4]);
#pragma unroll
      for (int kk = 0; kk < 4; kk++) {
        float4 wv = *reinterpret_cast<const float4*>(&Wl[(kc + k4 * 4 + kk) * HID + f4 * 4]);
#pragma unroll
        for (int j = 0; j < 4; j++) {
          float xvj = (kk == 0) ? xv[j].x : (kk == 1) ? xv[j].y : (kk == 2) ? xv[j].z : xv[j].w;
          acc[j][0] += xvj * wv.x;
          acc[j][1] += xvj * wv.y;
          acc[j][2] += xvj * wv.z;
          acc[j][3] += xvj * wv.w;
        }
      }
    }
  }
#pragma unroll
  for (int j = 0; j < 4; j++) {
    int node = node0 + ng * 4 + j;
    if (node < NN) {
      float s = dinv[node];
      h4 o;
      o.x = (_Float16)(acc[j][0] * s);
      o.y = (_Float16)(acc[j][1] * s);
      o.z = (_Float16)(acc[j][2] * s);
      o.w = (_Float16)(acc[j][3] * s);
      reinterpret_cast<h4*>(Gout)[(size_t)node * 8 + f4] = o;
    }
  }
}

// Pipelined gather loop (R17): 16 gathers in flight; next chunk's col
// indices prefetched while gathers outstanding; masked full-width tail.
#define GATH16_DECL                                                        \
  h2 v0 = G2[(size_t)ca.x * 16 + h], v1 = G2[(size_t)ca.y * 16 + h],       \
     v2 = G2[(size_t)ca.z * 16 + h], v3 = G2[(size_t)ca.w * 16 + h],       \
     v4 = G2[(size_t)cb.x * 16 + h], v5 = G2[(size_t)cb.y * 16 + h],       \
     v6 = G2[(size_t)cb.z * 16 + h], v7 = G2[(size_t)cb.w * 16 + h],       \
     v8 = G2[(size_t)cc.x * 16 + h], v9 = G2[(size_t)cc.y * 16 + h],       \
     v10 = G2[(size_t)cc.z * 16 + h], v11 = G2[(size_t)cc.w * 16 + h],     \
     v12 = G2[(size_t)cd.x * 16 + h], v13 = G2[(size_t)cd.y * 16 + h],     \
     v14 = G2[(size_t)cd.z * 16 + h], v15 = G2[(size_t)cd.w * 16 + h];

#define ACC16                                                              \
  ax0 += (float)v0.x; ay0 += (float)v0.y; ax1 += (float)v1.x; ay1 += (float)v1.y;   \
  ax2 += (float)v2.x; ay2 += (float)v2.y; ax3 += (float)v3.x; ay3 += (float)v3.y;   \
  ax0 += (float)v4.x; ay0 += (float)v4.y; ax1 += (float)v5.x; ay1 += (float)v5.y;   \
  ax2 += (float)v6.x; ay2 += (float)v6.y; ax3 += (float)v7.x; ay3 += (float)v7.y;   \
  ax0 += (float)v8.x; ay0 += (float)v8.y; ax1 += (float)v9.x; ay1 += (float)v9.y;   \
  ax2 += (float)v10.x; ay2 += (float)v10.y; ax3 += (float)v11.x; ay3 += (float)v11.y; \
  ax0 += (float)v12.x; ay0 += (float)v12.y; ax1 += (float)v13.x; ay1 += (float)v13.y; \
  ax2 += (float)v14.x; ay2 += (float)v14.y; ax3 += (float)v15.x; ay3 += (float)v15.y;

#define AGG_GATHER_LOOP                                                    \
  int i = beg;                                                             \
  int nch = (end - beg) >> 4;                                              \
  if (nch > 0) {                                                           \
    i4u ca = NTL4(&col[i]);                                                \
    i4u cb = NTL4(&col[i + 4]);                                            \
    i4u cc = NTL4(&col[i + 8]);                                            \
    i4u cd = NTL4(&col[i + 12]);                                           \
    i += 16;                                                               \
    for (int k = 1; k < nch; k++) {                                        \
      GATH16_DECL;                                                         \
      i4u na = NTL4(&col[i]);                                              \
      i4u nb = NTL4(&col[i + 4]);                                          \
      i4u nc = NTL4(&col[i + 8]);                                          \
      i4u nd = NTL4(&col[i + 12]);                                         \
      i += 16;                                                             \
      ACC16;                                                               \
      ca = na; cb = nb; cc = nc; cd = nd;                                  \
    }                                                                      \
    { GATH16_DECL; ACC16; }                                                \
  }                                                                        \
  int rem = end - i;                                                       \
  if (rem > 0) {                                                           \
    int e1 = end - 1;                                                      \
    int j1 = (i + 1 > e1) ? e1 : i + 1;                                    \
    int j2 = (i + 2 > e1) ? e1 : i + 2;                                    \
    int j3 = (i + 3 > e1) ? e1 : i + 3;                                    \
    int j4 = (i + 4 > e1) ? e1 : i + 4;                                    \
    int j5 = (i + 5 > e1) ? e1 : i + 5;                                    \
    int j6 = (i + 6 > e1) ? e1 : i + 6;                                    \
    int j7 = (i + 7 > e1) ? e1 : i + 7;                                    \
    int j8 = (i + 8 > e1) ? e1 : i + 8;                                    \
    int j9 = (i + 9 > e1) ? e1 : i + 9;                                    \
    int j10 = (i + 10 > e1) ? e1 : i + 10;                                 \
    int j11 = (i + 11 > e1) ? e1 : i + 11;                                 \
    int j12 = (i + 12 > e1) ? e1 : i + 12;                                 \
    int j13 = (i + 13 > e1) ? e1 : i + 13;                                 \
    int j14 = (i + 14 > e1) ? e1 : i + 14;                                 \
    int j15 = (i + 15 > e1) ? e1 : i + 15;                                 \
    int c0 = NTL(&col[i]), c1 = NTL(&col[j1]), c2 = NTL(&col[j2]),         \
        c3 = NTL(&col[j3]), c4 = NTL(&col[j4]), c5 = NTL(&col[j5]),        \
        c6 = NTL(&col[j6]), c7 = NTL(&col[j7]), c8 = NTL(&col[j8]),        \
        c9 = NTL(&col[j9]), c10 = NTL(&col[j10]), c11 = NTL(&col[j11]),    \
        c12 = NTL(&col[j12]), c13 = NTL(&col[j13]), c14 = NTL(&col[j14]),  \
        c15 = NTL(&col[j15]);                                              \
    h2 w0 = G2[(size_t)c0 * 16 + h], w1 = G2[(size_t)c1 * 16 + h],         \
       w2 = G2[(size_t)c2 * 16 + h], w3 = G2[(size_t)c3 * 16 + h],         \
       w4 = G2[(size_t)c4 * 16 + h], w5 = G2[(size_t)c5 * 16 + h],         \
       w6 = G2[(size_t)c6 * 16 + h], w7 = G2[(size_t)c7 * 16 + h],         \
       w8 = G2[(size_t)c8 * 16 + h], w9 = G2[(size_t)c9 * 16 + h],         \
       w10 = G2[(size_t)c10 * 16 + h], w11 = G2[(size_t)c11 * 16 + h],     \
       w12 = G2[(size_t)c12 * 16 + h], w13 = G2[(size_t)c13 * 16 + h],     \
       w14 = G2[(size_t)c14 * 16 + h], w15 = G2[(size_t)c15 * 16 + h];     \
    float m;                                                               \
    ax0 += (float)w0.x; ay0 += (float)w0.y;                                \
    m = (1 < rem) ? 1.f : 0.f; ax1 = fmaf(m, (float)w1.x, ax1); ay1 = fmaf(m, (float)w1.y, ay1);   \
    m = (2 < rem) ? 1.f : 0.f; ax2 = fmaf(m, (float)w2.x, ax2); ay2 = fmaf(m, (float)w2.y, ay2);   \
    m = (3 < rem) ? 1.f : 0.f; ax3 = fmaf(m, (float)w3.x, ax3); ay3 = fmaf(m, (float)w3.y, ay3);   \
    m = (4 < rem) ? 1.f : 0.f; ax0 = fmaf(m, (float)w4.x, ax0); ay0 = fmaf(m, (float)w4.y, ay0);   \
    m = (5 < rem) ? 1.f : 0.f; ax1 = fmaf(m, (float)w5.x, ax1); ay1 = fmaf(m, (float)w5.y, ay1);   \
    m = (6 < rem) ? 1.f : 0.f; ax2 = fmaf(m, (float)w6.x, ax2); ay2 = fmaf(m, (float)w6.y, ay2);   \
    m = (7 < rem) ? 1.f : 0.f; ax3 = fmaf(m, (float)w7.x, ax3); ay3 = fmaf(m, (float)w7.y, ay3);   \
    m = (8 < rem) ? 1.f : 0.f; ax0 = fmaf(m, (float)w8.x, ax0); ay0 = fmaf(m, (float)w8.y, ay0);   \
    m = (9 < rem) ? 1.f : 0.f; ax1 = fmaf(m, (float)w9.x, ax1); ay1 = fmaf(m, (float)w9.y, ay1);   \
    m = (10 < rem) ? 1.f : 0.f; ax2 = fmaf(m, (float)w10.x, ax2); ay2 = fmaf(m, (float)w10.y, ay2); \
    m = (11 < rem) ? 1.f : 0.f; ax3 = fmaf(m, (float)w11.x, ax3); ay3 = fmaf(m, (float)w11.y, ay3); \
    m = (12 < rem) ? 1.f : 0.f; ax0 = fmaf(m, (float)w12.x, ax0); ay0 = fmaf(m, (float)w12.y, ay0); \
    m = (13 < rem) ? 1.f : 0.f; ax1 = fmaf(m, (float)w13.x, ax1); ay1 = fmaf(m, (float)w13.y, ay1); \
    m = (14 < rem) ? 1.f : 0.f; ax2 = fmaf(m, (float)w14.x, ax2); ay2 = fmaf(m, (float)w14.y, ay2); \
    m = (15 < rem) ? 1.f : 0.f; ax3 = fmaf(m, (float)w15.x, ax3); ay3 = fmaf(m, (float)w15.y, ay3); \
  }                                                                        \
  ax0 += ax1 + ax2 + ax3;                                                  \
  ay0 += ay1 + ay2 + ay3;

// Pass 1: gather lower-half srcs only (G rows < HALFN: 3.2MB, L2-resident
// on every XCD) + self-loop term; raw sums -> Pbuf fp32 (NT, no dinv/bias).
__global__ __launch_bounds__(256) void k_aggp1(const _Float16* __restrict__ Gin,
                                               const int* __restrict__ col,
                                               const int* __restrict__ row_ptr,
                                               const int* __restrict__ mid,
                                               float* __restrict__ Pbuf) {
  const h2* G2 = reinterpret_cast<const h2*>(Gin);
  int t = threadIdx.x;
  int h = t & 15;
  int slot = t >> 4;
  int n = blockIdx.x * 16 + slot;
  int beg = row_ptr[n], end = mid[n];

  h2 g0 = G2[(size_t)n * 16 + h];  // self-loop term
  float ax0 = (float)g0.x, ay0 = (float)g0.y;
  float ax1 = 0.f, ay1 = 0.f, ax2 = 0.f, ay2 = 0.f, ax3 = 0.f, ay3 = 0.f;

  AGG_GATHER_LOOP;

  f2 v;
  v.x = ax0;
  v.y = ay0;
  __builtin_nontemporal_store(v, &reinterpret_cast<f2*>(Pbuf)[(size_t)n * 16 + h]);
}

// Pass 2 (layers 1-2): gather upper-half srcs + Pbuf partial; dinv/bias/
// relu; fused next-layer GEMM -> G' fp16.
__global__ __launch_bounds__(256) void k_aggmm2(const _Float16* __restrict__ Gin,
                                                const int* __restrict__ col,
                                                const int* __restrict__ row_ptr,
                                                const int* __restrict__ mid,
                                                const float* __restrict__ Pbuf,
                                                const float* __restrict__ dinv,
                                                const float* __restrict__ bias,
                                                const float* __restrict__ Wn,
                                                _Float16* __restrict__ Gout) {
  __shared__ float Wl[HID * HID];   // 4 KB next-layer weights
  __shared__ float As[16][HID + 1]; // padded A rows
  const h2* G2 = reinterpret_cast<const h2*>(Gin);
  int t = threadIdx.x;
  int h = t & 15;
  int slot = t >> 4;
  int n = blockIdx.x * 16 + slot;
#pragma unroll
  for (int q = 0; q < 4; q++) Wl[t + 256 * q] = Wn[t + 256 * q];
  int beg = mid[n], end = row_ptr[n + 1];

  float ax0 = 0.f, ay0 = 0.f;
  float ax1 = 0.f, ay1 = 0.f, ax2 = 0.f, ay2 = 0.f, ax3 = 0.f, ay3 = 0.f;

  AGG_GATHER_LOOP;

  f2 p = __builtin_nontemporal_load(&reinterpret_cast<const f2*>(Pbuf)[(size_t)n * 16 + h]);
  ax0 += p.x;
  ay0 += p.y;

  float s = dinv[n];
  float2 b = reinterpret_cast<const float2*>(bias)[h];
  float a0 = fmaxf(s * ax0 + b.x, 0.f);  // layers 1-2 always relu
  float a1 = fmaxf(s * ay0 + b.y, 0.f);
  As[slot][2 * h] = a0;
  As[slot][2 * h + 1] = a1;
  __syncthreads();

  // G'[n][2h,2h+1] = dinv[n] * sum_k A[n][k] * Wn[k][2h,2h+1]
  float o0 = 0.f, o1 = 0.f;
#pragma unroll
  for (int k = 0; k < HID; k++) {
    float a = As[slot][k];  // broadcast across the 16 h-lanes
    o0 += a * Wl[k * HID + 2 * h];
    o1 += a * Wl[k * HID + 2 * h + 1];
  }
  h2 o;
  o.x = (_Float16)(o0 * s);
  o.y = (_Float16)(o1 * s);
  reinterpret_cast<h2*>(Gout)[(size_t)n * 16 + h] = o;
}

// Pass 2 (final layer): gather upper half + Pbuf; no relu; fp32 out.
__global__ __launch_bounds__(256) void k_agg2(const _Float16* __restrict__ Gin,
                                              const int* __restrict__ col,
                                              const int* __restrict__ row_ptr,
                                              const int* __restrict__ mid,
                                              const float* __restrict__ Pbuf,
                                              const float* __restrict__ dinv,
                                              const float* __restrict__ bias,
                                              float* __restrict__ Xout) {
  const h2* G2 = reinterpret_cast<const h2*>(Gin);
  int t = threadIdx.x;
  int h = t & 15;
  int slot = t >> 4;
  int n = blockIdx.x * 16 + slot;
  int beg = mid[n], end = row_ptr[n + 1];

  float ax0 = 0.f, ay0 = 0.f;
  float ax1 = 0.f, ay1 = 0.f, ax2 = 0.f, ay2 = 0.f, ax3 = 0.f, ay3 = 0.f;

  AGG_GATHER_LOOP;

  f2 p = __builtin_nontemporal_load(&reinterpret_cast<const f2*>(Pbuf)[(size_t)n * 16 + h]);
  ax0 += p.x;
  ay0 += p.y;

  float s = dinv[n];
  float2 b = reinterpret_cast<const float2*>(bias)[h];
  float2 v;
  v.x = s * ax0 + b.x;
  v.y = s * ay0 + b.y;
  reinterpret_cast<float2*>(Xout)[(size_t)n * 16 + h] = v;
}

// Mean-pool: batch is sorted, so flush-on-graph-change keeps atomics rare.
__global__ __launch_bounds__(256) void k_pool(const float* __restrict__ X,
                                              const int* __restrict__ batch,
                                              float* __restrict__ sums,
                                              int* __restrict__ counts) {
  int t = threadIdx.x;
  int f = t & 31, slot = t >> 5;
  int base = blockIdx.x * 512;
  float acc = 0.f;
  int cnt = 0, cur = -1;
  for (int i = 0; i < 64; i++) {
    int n = base + slot + i * 8;
    if (n >= NN) break;
    int g = batch[n];
    if (g != cur) {
      if (cur >= 0) {
        atomicAdd(&sums[cur * HID + f], acc);
        if (f == 0) atomicAdd(&counts[cur], cnt);
      }
      cur = g;
      acc = 0.f;
      cnt = 0;
    }
    acc += X[(size_t)n * HID + f];
    cnt++;
  }
  if (cur >= 0) {
    atomicAdd(&sums[cur * HID + f], acc);
    if (f == 0) atomicAdd(&counts[cur], cnt);
  }
}

__global__ void k_fc(const float* __restrict__ sums, const int* __restrict__ counts,
                     const float* __restrict__ Wfc, const float* __restrict__ bfc,
                     float* __restrict__ out) {
  int idx = blockIdx.x * 256 + threadIdx.x;
  if (idx >= NGR * NC) return;
  int g = idx / NC, c = idx % NC;
  float inv = 1.f / fmaxf((float)counts[g], 1.f);
  float acc = bfc[c];
#pragma unroll
  for (int k = 0; k < HID; k++) acc += sums[g * HID + k] * inv * Wfc[k * NC + c];
  out[idx] = acc;
}

extern "C" void kernel_launch(void* const* d_in, const int* in_sizes, int n_in,
                              void* d_out, int out_size, void* d_ws, size_t ws_size,
                              hipStream_t stream) {
  (void)in_sizes; (void)n_in; (void)out_size; (void)ws_size;
  const float* x = (const float*)d_in[0];
  const int* ei = (const int*)d_in[1];
  const int* batch = (const int*)d_in[2];
  const float* W1 = (const float*)d_in[3];
  const float* b1 = (const float*)d_in[4];
  const float* W2 = (const float*)d_in[5];
  const float* b2 = (const float*)d_in[6];
  const float* W3 = (const float*)d_in[7];
  const float* b3 = (const float*)d_in[8];
  const float* Wfc = (const float*)d_in[9];
  const float* bfc = (const float*)d_in[10];
  float* out = (float*)d_out;

  char* ws = (char*)d_ws;
  size_t off = 0;
  auto alloc = [&](size_t bytes) -> void* {
    void* p = ws + off;
    off = (off + bytes + 255) & ~(size_t)255;
    return p;
  };
  float* dinv = (float*)alloc((size_t)NN * 4);
  int* row_ptr = (int*)alloc((size_t)(NN + 1) * 4);
  int* mid = (int*)alloc((size_t)NN * 4);
  int* bcur = (int*)alloc(NBUK * 4);
  int* col = (int*)alloc((size_t)EE * 4);
  // Union region: bpair (CSR build only) overlaps G1/G2/Abuf (layer phase).
  size_t bpair_bytes = (size_t)NBUK * BSLACK * 8;          // 27.4 MB
  size_t gbuf_bytes = (size_t)NN * HID * 2;                // 6.4 MB (fp16)
  size_t abuf_bytes = (size_t)NN * HID * 4;                // 12.8 MB (fp32)
  size_t need = 2 * gbuf_bytes + abuf_bytes;               // G1 + G2 + Abuf
  char* uni = (char*)alloc(bpair_bytes > need ? bpair_bytes : need);
  long long* bpair = (long long*)uni;
  _Float16* G1 = (_Float16*)uni;
  _Float16* G2b = (_Float16*)(uni + gbuf_bytes);
  float* Abuf = (float*)(uni + 2 * gbuf_bytes);
  float* Pbuf = (float*)alloc((size_t)NN * HID * 4);       // 12.8 MB partials
  float* sums = (float*)alloc((size_t)NGR * HID * 4);
  int* counts = (int*)alloc((size_t)NGR * 4);

  hipMemsetAsync(sums, 0, (size_t)NGR * HID * 4, stream);
  hipMemsetAsync(counts, 0, (size_t)NGR * 4, stream);

  k_init<<<1, NBUK, 0, stream>>>(bcur);
  k_bucket<<<(EE + TILE - 1) / TILE, 1024, 0, stream>>>(ei, bcur, bpair);
  k_place<<<NBUK, 1024, 0, stream>>>(bpair, bcur, dinv, row_ptr, mid, col);

  k_gemm<FIN><<<(NN + 127) / 128, 256, 0, stream>>>(x, W1, dinv, G1);
  // Layer 1: p1 (lower half + self) -> Pbuf; p2 (upper half) + fused GEMM
  k_aggp1<<<NN / 16, 256, 0, stream>>>(G1, col, row_ptr, mid, Pbuf);
  k_aggmm2<<<NN / 16, 256, 0, stream>>>(G1, col, row_ptr, mid, Pbuf, dinv, b1, W2, G2b);
  // Layer 2 (reuse G1 buffer for G3)
  k_aggp1<<<NN / 16, 256, 0, stream>>>(G2b, col, row_ptr, mid, Pbuf);
  k_aggmm2<<<NN / 16, 256, 0, stream>>>(G2b, col, row_ptr, mid, Pbuf, dinv, b2, W3, G1);
  // Layer 3: final agg, fp32 out for pool
  k_aggp1<<<NN / 16, 256, 0, stream>>>(G1, col, row_ptr, mid, Pbuf);
  k_agg2<<<NN / 16, 256, 0, stream>>>(G1, col, row_ptr, mid, Pbuf, dinv, b3, Abuf);

  k_pool<<<(NN + 511) / 512, 256, 0, stream>>>(Abuf, batch, sums, counts);
  k_fc<<<(NGR * NC + 255) / 256, 256, 0, stream>>>(sums, counts, Wfc, bfc, out);
}

// Round 5
// 351.994 us; speedup vs baseline: 1.1387x; 1.1387x over previous
//
#include <hip/hip_runtime.h>

// GCN: 3x GCNConv(sym-norm, self-loops) + ReLU, mean-pool per graph, FC.
// Strategy: fold dinv into per-layer G = dinv .* (X@W); build dst-CSR once
// per call so aggregation is atomic-free.
// R1-R7: store-coalescing chase falsified. R8: zero global atomics in CSR
//   build. R9/R11/R12: L2-residency bets failed. R10: G fp16 (1 line/edge).
//   R13: 1024-wide bucket/place -> 405us. R14: fuse next-layer GEMM into
//   agg epilogue -> 376us (agg 59us, FETCH 121MB, VALUBusy 28%).
// R15/16: XCD feature-split FALSIFIED (FETCH halved, dur worse).
// R17: pipelined gather (chunk16, col prefetch, int4 cols, masked tail)
//   -> 358.7us; agg 48us, VALUBusy 44%, FETCH 103MB.
// R18: 2-pass src-partitioned agg FALSIFIED: per-pass 31us at half edges
//   (worse per edge) despite guaranteed 3.2MB L2-resident gather set.
//   => gather is request-ISSUE (TA address-rate) bound, NOT latency bound.
//   (Top-5 fills = harness 256MiB ws-poison, not ours.)
// R19: revert to R17 structure; gather layout 16lanes x 4B -> 4 lanes x
//   16B (h8 dwordx4). Same 64B line/edge, 4x fewer lane-addresses and
//   load instructions. Predict agg 48 -> ~30us, FETCH unchanged.

#include <hip/hip_fp16.h>

#define NN 100000
#define EE 3200000
#define FIN 128
#define HID 32
#define NGR 256
#define NC 10
#define NBUK 256
#define BRANGE 391    // 256*391 = 100096 >= NN
#define BSLACK 13400  // mean 12500, sd ~112 -> ~8 sigma slack (input is fixed)
#define TILE 8192

typedef _Float16 h4 __attribute__((ext_vector_type(4)));
typedef _Float16 h8 __attribute__((ext_vector_type(8)));
typedef int i4u __attribute__((ext_vector_type(4), aligned(4)));

#define NTL(p) __builtin_nontemporal_load(p)
#define NTL4(p) __builtin_nontemporal_load(reinterpret_cast<const i4u*>(p))

__global__ void k_init(int* __restrict__ bcur) {
  int t = threadIdx.x;
  if (t < NBUK) bcur[t] = t * BSLACK;
}

// Pass A: LDS multisplit of one 8192-edge tile into 256 dst-buckets.
__global__ __launch_bounds__(1024) void k_bucket(const int* __restrict__ ei,
                                                 int* __restrict__ bcur,
                                                 long long* __restrict__ bpair) {
  __shared__ int hist[NBUK];
  __shared__ int bexc[NBUK];
  __shared__ int cnt[NBUK];
  __shared__ int gofs[NBUK];
  __shared__ long long sorted[TILE];  // 64 KB
  int t = threadIdx.x;
  const int* src = ei;
  const int* dst = ei + EE;
  int e0 = blockIdx.x * TILE;
  int tn = EE - e0;
  if (tn > TILE) tn = TILE;

  if (t < NBUK) { hist[t] = 0; cnt[t] = 0; }
  __syncthreads();

  for (int i = t; i < tn; i += 1024) {
    int d = __builtin_nontemporal_load(&dst[e0 + i]);
    atomicAdd(&hist[d / BRANGE], 1);
  }
  __syncthreads();

  int hv = 0;
  if (t < NBUK) { hv = hist[t]; bexc[t] = hv; }
  __syncthreads();
#pragma unroll
  for (int off = 1; off < NBUK; off <<= 1) {
    int x = 0;
    if (t < NBUK && t >= off) x = bexc[t - off];
    __syncthreads();
    if (t < NBUK) bexc[t] += x;
    __syncthreads();
  }
  if (t < NBUK) {
    int inc = bexc[t];
    bexc[t] = inc - hv;
    if (hv > 0) gofs[t] = atomicAdd(&bcur[t], hv);  // ~65K atomics total
  }
  __syncthreads();

  for (int i = t; i < tn; i += 1024) {
    int d = dst[e0 + i];
    int s = src[e0 + i];
    int q = d / BRANGE;
    int p = bexc[q] + atomicAdd(&cnt[q], 1);
    sorted[p] = ((long long)(unsigned)d << 32) | (unsigned)s;
  }
  __syncthreads();

  for (int i = t; i < tn; i += 1024) {
    long long pr = sorted[i];
    int q = (int)(unsigned)(pr >> 32) / BRANGE;
    __builtin_nontemporal_store(pr, &bpair[(size_t)gofs[q] + (i - bexc[q])]);
  }
}

// Fused CSR finalize: one 1024-thread block per bucket, zero global atomics.
__global__ __launch_bounds__(1024) void k_place(const long long* __restrict__ bpair,
                                                const int* __restrict__ bcur,
                                                float* __restrict__ dinv,
                                                int* __restrict__ row_ptr,
                                                int* __restrict__ col) {
  __shared__ int bs[NBUK];
  __shared__ int cnt[BRANGE];
  __shared__ int sc[1024];
  int b = blockIdx.x, t = threadIdx.x;

  if (t < NBUK) bs[t] = bcur[t] - t * BSLACK;
  __syncthreads();
#pragma unroll
  for (int off = 1; off < NBUK; off <<= 1) {
    int x = 0;
    if (t < NBUK && t >= off) x = bs[t - off];
    __syncthreads();
    if (t < NBUK) bs[t] += x;
    __syncthreads();
  }
  __syncthreads();
  int sz = bcur[b] - b * BSLACK;
  int colbase = bs[b] - sz;

  if (t < BRANGE) cnt[t] = 0;
  __syncthreads();

  int lo = b * BRANGE;
  int nnode = NN - lo;
  if (nnode > BRANGE) nnode = BRANGE;
  size_t e0 = (size_t)b * BSLACK;

  for (int i = t; i < sz; i += 1024) {
    long long pr = bpair[e0 + i];
    int d = (int)(unsigned)(pr >> 32);
    atomicAdd(&cnt[d - lo], 1);
  }
  __syncthreads();

  int v = (t < BRANGE) ? cnt[t] : 0;
  sc[t] = v;
  __syncthreads();
#pragma unroll
  for (int off = 1; off < 1024; off <<= 1) {
    int x = (t >= off) ? sc[t - off] : 0;
    __syncthreads();
    sc[t] += x;
    __syncthreads();
  }
  int excl = sc[t] - v;
  if (t < nnode) {
    row_ptr[lo + t] = colbase + excl;
    dinv[lo + t] = rsqrtf((float)(v + 1));  // +1 = self-loop
  }
  if (t < BRANGE) cnt[t] = colbase + excl;  // absolute cursor
  if (b == NBUK - 1 && t == 0) row_ptr[NN] = EE;
  __syncthreads();

  for (int i = t; i < sz; i += 1024) {
    long long pr = bpair[e0 + i];
    int d = (int)(unsigned)(pr >> 32);
    int s = (int)(unsigned)(pr & 0xffffffffLL);
    int pos = atomicAdd(&cnt[d - lo], 1);
    col[pos] = s;
  }
}

// G = dinv .* (X @ W), stored fp16 [node][32] (64B rows = 1 cache line).
template <int K>
__global__ __launch_bounds__(256) void k_gemm(const float* __restrict__ X,
                                              const float* __restrict__ W,
                                              const float* __restrict__ dinv,
                                              _Float16* __restrict__ Gout) {
  __shared__ float Wl[K * HID];
  __shared__ float xs[128 * 36];
  int t = threadIdx.x;
  for (int i = t; i < K * HID; i += 256) Wl[i] = W[i];
  int node0 = blockIdx.x * 128;
  int ng = t >> 3, f4 = t & 7;
  float acc[4][4];
#pragma unroll
  for (int j = 0; j < 4; j++)
#pragma unroll
    for (int c = 0; c < 4; c++) acc[j][c] = 0.f;

  for (int kc = 0; kc < K; kc += 32) {
    __syncthreads();
#pragma unroll
    for (int j = 0; j < 4; j++) {
      int idx = t + 256 * j;
      int r = idx >> 3, c4 = idx & 7;
      int row = node0 + r;
      if (row >= NN) row = NN - 1;
      float4 v = *reinterpret_cast<const float4*>(&X[(size_t)row * K + kc + c4 * 4]);
      *reinterpret_cast<float4*>(&xs[r * 36 + c4 * 4]) = v;
    }
    __syncthreads();
#pragma unroll
    for (int k4 = 0; k4 < 8; k4++) {
      float4 xv[4];
#pragma unroll
      for (int j = 0; j < 4; j++)
        xv[j] = *reinterpret_cast<const float4*>(&xs[(ng * 4 + j) * 36 + k4 * 4]);
#pragma unroll
      for (int kk = 0; kk < 4; kk++) {
        float4 wv = *reinterpret_cast<const float4*>(&Wl[(kc + k4 * 4 + kk) * HID + f4 * 4]);
#pragma unroll
        for (int j = 0; j < 4; j++) {
          float xvj = (kk == 0) ? xv[j].x : (kk == 1) ? xv[j].y : (kk == 2) ? xv[j].z : xv[j].w;
          acc[j][0] += xvj * wv.x;
          acc[j][1] += xvj * wv.y;
          acc[j][2] += xvj * wv.z;
          acc[j][3] += xvj * wv.w;
        }
      }
    }
  }
#pragma unroll
  for (int j = 0; j < 4; j++) {
    int node = node0 + ng * 4 + j;
    if (node < NN) {
      float s = dinv[node];
      h4 o;
      o.x = (_Float16)(acc[j][0] * s);
      o.y = (_Float16)(acc[j][1] * s);
      o.z = (_Float16)(acc[j][2] * s);
      o.w = (_Float16)(acc[j][3] * s);
      reinterpret_cast<h4*>(Gout)[(size_t)node * 8 + f4] = o;
    }
  }
}

// R19 gather: 4 lanes/node, each lane loads the full 16B (8 feats) h8
// quarter-row per edge -> 4 lane-addresses per 64B line instead of 16.
// Chunk 8 edges in flight; col indices prefetched one chunk ahead;
// masked full-width tail. Caller declares: l, G8, col, beg, end,
// accA[8], accB[8].
#define GATH8_DECL                                                         \
  h8 v0 = G8[(size_t)ca.x * 4 + l], v1 = G8[(size_t)ca.y * 4 + l],         \
     v2 = G8[(size_t)ca.z * 4 + l], v3 = G8[(size_t)ca.w * 4 + l],         \
     v4 = G8[(size_t)cb.x * 4 + l], v5 = G8[(size_t)cb.y * 4 + l],         \
     v6 = G8[(size_t)cb.z * 4 + l], v7 = G8[(size_t)cb.w * 4 + l];

#define ACC8                                                               \
  _Pragma("unroll") for (int f = 0; f < 8; f++) {                          \
    accA[f] += (float)v0[f];                                               \
    accB[f] += (float)v1[f];                                               \
    accA[f] += (float)v2[f];                                               \
    accB[f] += (float)v3[f];                                               \
    accA[f] += (float)v4[f];                                               \
    accB[f] += (float)v5[f];                                               \
    accA[f] += (float)v6[f];                                               \
    accB[f] += (float)v7[f];                                               \
  }

#define AGG_GATHER_LOOP                                                    \
  int i = beg;                                                             \
  int nch = (end - beg) >> 3;                                              \
  if (nch > 0) {                                                           \
    i4u ca = NTL4(&col[i]);                                                \
    i4u cb = NTL4(&col[i + 4]);                                            \
    i += 8;                                                                \
    for (int k = 1; k < nch; k++) {                                        \
      GATH8_DECL;                                                          \
      i4u na = NTL4(&col[i]);                                              \
      i4u nb = NTL4(&col[i + 4]);                                          \
      i += 8;                                                              \
      ACC8;                                                                \
      ca = na; cb = nb;                                                    \
    }                                                                      \
    { GATH8_DECL; ACC8; }                                                  \
  }                                                                        \
  int rem = end - i;                                                       \
  if (rem > 0) {                                                           \
    int e1 = end - 1;                                                      \
    int j1 = (i + 1 > e1) ? e1 : i + 1;                                    \
    int j2 = (i + 2 > e1) ? e1 : i + 2;                                    \
    int j3 = (i + 3 > e1) ? e1 : i + 3;                                    \
    int j4 = (i + 4 > e1) ? e1 : i + 4;                                    \
    int j5 = (i + 5 > e1) ? e1 : i + 5;                                    \
    int j6 = (i + 6 > e1) ? e1 : i + 6;                                    \
    int j7 = (i + 7 > e1) ? e1 : i + 7;                                    \
    int c0 = NTL(&col[i]), c1 = NTL(&col[j1]), c2 = NTL(&col[j2]),         \
        c3 = NTL(&col[j3]), c4 = NTL(&col[j4]), c5 = NTL(&col[j5]),        \
        c6 = NTL(&col[j6]), c7 = NTL(&col[j7]);                            \
    h8 w0 = G8[(size_t)c0 * 4 + l], w1 = G8[(size_t)c1 * 4 + l],           \
       w2 = G8[(size_t)c2 * 4 + l], w3 = G8[(size_t)c3 * 4 + l],           \
       w4 = G8[(size_t)c4 * 4 + l], w5 = G8[(size_t)c5 * 4 + l],           \
       w6 = G8[(size_t)c6 * 4 + l], w7 = G8[(size_t)c7 * 4 + l];           \
    float m;                                                               \
    _Pragma("unroll") for (int f = 0; f < 8; f++) accA[f] += (float)w0[f]; \
    m = (1 < rem) ? 1.f : 0.f;                                             \
    _Pragma("unroll") for (int f = 0; f < 8; f++) accB[f] = fmaf(m, (float)w1[f], accB[f]); \
    m = (2 < rem) ? 1.f : 0.f;                                             \
    _Pragma("unroll") for (int f = 0; f < 8; f++) accA[f] = fmaf(m, (float)w2[f], accA[f]); \
    m = (3 < rem) ? 1.f : 0.f;                                             \
    _Pragma("unroll") for (int f = 0; f < 8; f++) accB[f] = fmaf(m, (float)w3[f], accB[f]); \
    m = (4 < rem) ? 1.f : 0.f;                                             \
    _Pragma("unroll") for (int f = 0; f < 8; f++) accA[f] = fmaf(m, (float)w4[f], accA[f]); \
    m = (5 < rem) ? 1.f : 0.f;                                             \
    _Pragma("unroll") for (int f = 0; f < 8; f++) accB[f] = fmaf(m, (float)w5[f], accB[f]); \
    m = (6 < rem) ? 1.f : 0.f;                                             \
    _Pragma("unroll") for (int f = 0; f < 8; f++) accA[f] = fmaf(m, (float)w6[f], accA[f]); \
    m = (7 < rem) ? 1.f : 0.f;                                             \
    _Pragma("unroll") for (int f = 0; f < 8; f++) accB[f] = fmaf(m, (float)w7[f], accB[f]); \
  }                                                                        \
  _Pragma("unroll") for (int f = 0; f < 8; f++) accA[f] += accB[f];

// Fused agg + next-layer GEMM (layers 1-2). Per block: 64 nodes x 32 feats,
// 4 lanes/node (8 feats each).
__global__ __launch_bounds__(256) void k_aggmm(const _Float16* __restrict__ Gin,
                                               const int* __restrict__ col,
                                               const int* __restrict__ row_ptr,
                                               const float* __restrict__ dinv,
                                               const float* __restrict__ bias,
                                               const float* __restrict__ Wn,
                                               _Float16* __restrict__ Gout) {
  __shared__ float Wl[HID * HID];    // 4 KB next-layer weights
  __shared__ float As[64][HID + 1];  // padded A rows (8.4 KB)
  const h8* G8 = reinterpret_cast<const h8*>(Gin);
  int t = threadIdx.x;
  int l = t & 3;
  int slot = t >> 2;
  int n = blockIdx.x * 64 + slot;
  int nl = (n < NN) ? n : NN - 1;  // clamp loads; all threads reach syncs
#pragma unroll
  for (int q = 0; q < 4; q++) Wl[t + 256 * q] = Wn[t + 256 * q];
  int beg = row_ptr[nl], end = row_ptr[nl + 1];

  float accA[8], accB[8];
  h8 g0 = G8[(size_t)nl * 4 + l];  // self-loop term
#pragma unroll
  for (int f = 0; f < 8; f++) { accA[f] = (float)g0[f]; accB[f] = 0.f; }

  AGG_GATHER_LOOP;

  float s = dinv[nl];
  float4 bv0 = reinterpret_cast<const float4*>(bias)[2 * l];
  float4 bv1 = reinterpret_cast<const float4*>(bias)[2 * l + 1];
  float bb[8] = {bv0.x, bv0.y, bv0.z, bv0.w, bv1.x, bv1.y, bv1.z, bv1.w};
#pragma unroll
  for (int f = 0; f < 8; f++)
    As[slot][8 * l + f] = fmaxf(s * accA[f] + bb[f], 0.f);  // layers 1-2 relu
  __syncthreads();

  // G'[n][8l+f] = dinv[n] * sum_k A[n][k] * Wn[k][8l+f]
  float o[8];
#pragma unroll
  for (int f = 0; f < 8; f++) o[f] = 0.f;
#pragma unroll
  for (int k = 0; k < HID; k++) {
    float a = As[slot][k];  // broadcast
#pragma unroll
    for (int f = 0; f < 8; f++) o[f] += a * Wl[k * HID + 8 * l + f];
  }
  if (n < NN) {
    h8 ov;
#pragma unroll
    for (int f = 0; f < 8; f++) ov[f] = (_Float16)(o[f] * s);
    reinterpret_cast<h8*>(Gout)[(size_t)n * 4 + l] = ov;
  }
}

// Final-layer agg (no relu, fp32 out for pool). Same 4-lane gather.
__global__ __launch_bounds__(256) void k_agg(const _Float16* __restrict__ Gin,
                                             const int* __restrict__ col,
                                             const int* __restrict__ row_ptr,
                                             const float* __restrict__ dinv,
                                             const float* __restrict__ bias,
                                             float* __restrict__ Xout) {
  const h8* G8 = reinterpret_cast<const h8*>(Gin);
  int t = threadIdx.x;
  int l = t & 3;
  int slot = t >> 2;
  int n = blockIdx.x * 64 + slot;
  if (n >= NN) return;
  int beg = row_ptr[n], end = row_ptr[n + 1];

  float accA[8], accB[8];
  h8 g0 = G8[(size_t)n * 4 + l];  // self-loop term
#pragma unroll
  for (int f = 0; f < 8; f++) { accA[f] = (float)g0[f]; accB[f] = 0.f; }

  AGG_GATHER_LOOP;

  float s = dinv[n];
  float4 bv0 = reinterpret_cast<const float4*>(bias)[2 * l];
  float4 bv1 = reinterpret_cast<const float4*>(bias)[2 * l + 1];
  float4 o0, o1;
  o0.x = s * accA[0] + bv0.x;
  o0.y = s * accA[1] + bv0.y;
  o0.z = s * accA[2] + bv0.z;
  o0.w = s * accA[3] + bv0.w;
  o1.x = s * accA[4] + bv1.x;
  o1.y = s * accA[5] + bv1.y;
  o1.z = s * accA[6] + bv1.z;
  o1.w = s * accA[7] + bv1.w;
  reinterpret_cast<float4*>(Xout)[(size_t)n * 8 + 2 * l] = o0;
  reinterpret_cast<float4*>(Xout)[(size_t)n * 8 + 2 * l + 1] = o1;
}

// Mean-pool: batch is sorted, so flush-on-graph-change keeps atomics rare.
__global__ __launch_bounds__(256) void k_pool(const float* __restrict__ X,
                                              const int* __restrict__ batch,
                                              float* __restrict__ sums,
                                              int* __restrict__ counts) {
  int t = threadIdx.x;
  int f = t & 31, slot = t >> 5;
  int base = blockIdx.x * 512;
  float acc = 0.f;
  int cnt = 0, cur = -1;
  for (int i = 0; i < 64; i++) {
    int n = base + slot + i * 8;
    if (n >= NN) break;
    int g = batch[n];
    if (g != cur) {
      if (cur >= 0) {
        atomicAdd(&sums[cur * HID + f], acc);
        if (f == 0) atomicAdd(&counts[cur], cnt);
      }
      cur = g;
      acc = 0.f;
      cnt = 0;
    }
    acc += X[(size_t)n * HID + f];
    cnt++;
  }
  if (cur >= 0) {
    atomicAdd(&sums[cur * HID + f], acc);
    if (f == 0) atomicAdd(&counts[cur], cnt);
  }
}

__global__ void k_fc(const float* __restrict__ sums, const int* __restrict__ counts,
                     const float* __restrict__ Wfc, const float* __restrict__ bfc,
                     float* __restrict__ out) {
  int idx = blockIdx.x * 256 + threadIdx.x;
  if (idx >= NGR * NC) return;
  int g = idx / NC, c = idx % NC;
  float inv = 1.f / fmaxf((float)counts[g], 1.f);
  float acc = bfc[c];
#pragma unroll
  for (int k = 0; k < HID; k++) acc += sums[g * HID + k] * inv * Wfc[k * NC + c];
  out[idx] = acc;
}

extern "C" void kernel_launch(void* const* d_in, const int* in_sizes, int n_in,
                              void* d_out, int out_size, void* d_ws, size_t ws_size,
                              hipStream_t stream) {
  (void)in_sizes; (void)n_in; (void)out_size; (void)ws_size;
  const float* x = (const float*)d_in[0];
  const int* ei = (const int*)d_in[1];
  const int* batch = (const int*)d_in[2];
  const float* W1 = (const float*)d_in[3];
  const float* b1 = (const float*)d_in[4];
  const float* W2 = (const float*)d_in[5];
  const float* b2 = (const float*)d_in[6];
  const float* W3 = (const float*)d_in[7];
  const float* b3 = (const float*)d_in[8];
  const float* Wfc = (const float*)d_in[9];
  const float* bfc = (const float*)d_in[10];
  float* out = (float*)d_out;

  char* ws = (char*)d_ws;
  size_t off = 0;
  auto alloc = [&](size_t bytes) -> void* {
    void* p = ws + off;
    off = (off + bytes + 255) & ~(size_t)255;
    return p;
  };
  float* dinv = (float*)alloc((size_t)NN * 4);
  int* row_ptr = (int*)alloc((size_t)(NN + 1) * 4);
  int* bcur = (int*)alloc(NBUK * 4);
  int* col = (int*)alloc((size_t)EE * 4);
  // Union region: bpair (CSR build only) overlaps G1/G2/Abuf (layer phase).
  size_t bpair_bytes = (size_t)NBUK * BSLACK * 8;          // 27.4 MB
  size_t gbuf_bytes = (size_t)NN * HID * 2;                // 6.4 MB (fp16)
  size_t abuf_bytes = (size_t)NN * HID * 4;                // 12.8 MB (fp32)
  size_t need = 2 * gbuf_bytes + abuf_bytes;               // G1 + G2 + Abuf
  char* uni = (char*)alloc(bpair_bytes > need ? bpair_bytes : need);
  long long* bpair = (long long*)uni;
  _Float16* G1 = (_Float16*)uni;
  _Float16* G2b = (_Float16*)(uni + gbuf_bytes);
  float* Abuf = (float*)(uni + 2 * gbuf_bytes);
  float* sums = (float*)alloc((size_t)NGR * HID * 4);
  int* counts = (int*)alloc((size_t)NGR * 4);

  hipMemsetAsync(sums, 0, (size_t)NGR * HID * 4, stream);
  hipMemsetAsync(counts, 0, (size_t)NGR * 4, stream);

  k_init<<<1, NBUK, 0, stream>>>(bcur);
  k_bucket<<<(EE + TILE - 1) / TILE, 1024, 0, stream>>>(ei, bcur, bpair);
  k_place<<<NBUK, 1024, 0, stream>>>(bpair, bcur, dinv, row_ptr, col);

  k_gemm<FIN><<<(NN + 127) / 128, 256, 0, stream>>>(x, W1, dinv, G1);
  // Fused: A1 = relu(agg(G1)+b1); G2 = dinv.*(A1@W2)
  k_aggmm<<<(NN + 63) / 64, 256, 0, stream>>>(G1, col, row_ptr, dinv, b1, W2, G2b);
  // Fused: A2 = relu(agg(G2)+b2); G3 = dinv.*(A2@W3)  (reuse G1 buffer)
  k_aggmm<<<(NN + 63) / 64, 256, 0, stream>>>(G2b, col, row_ptr, dinv, b2, W3, G1);
  // Final: A3 = agg(G3)+b3 (no relu), fp32 for pool
  k_agg<<<(NN + 63) / 64, 256, 0, stream>>>(G1, col, row_ptr, dinv, b3, Abuf);

  k_pool<<<(NN + 511) / 512, 256, 0, stream>>>(Abuf, batch, sums, counts);
  k_fc<<<(NGR * NC + 255) / 256, 256, 0, stream>>>(sums, counts, Wfc, bfc, out);
}